// Round 10
// baseline (1528.678 us; speedup 1.0000x reference)
//
#include <hip/hip_runtime.h>

// Problem constants
#define NDRUG 50000
#define NDIS  50000
#define RR    5
#define FF    128
#define EFFD  128
#define OUTD  64
#define EE    400000
#define NCOL  (RR * OUTD)        // 320 columns in fused g / out layout [n][r*64+o]
#define NEDGE (RR * EE)          // 2,000,000 edges per direction

// Two-level bucket scheme
#define NBKT    196              // coarse buckets per (dir,r): dst>>8 (50000/256)
#define CAP     4096             // slot capacity per bucket (avg fill 2048, ~45 sigma headroom)
#define NGB     (2 * RR * NBKT)  // 1960 global buckets
#define QBKT    49               // buckets per dst-quarter (196 = 4*49)
#define STCAP   2048             // LDS staging entries per k_part block

// XCD partitioning for k_part: 8 partitions = dir(2) x dst-quarter(4)
#define NPART   8
#define NCHUNKE 64               // edge chunks per r
#define CHUNKE  (EE / NCHUNKE)   // 6250 edges per chunk

typedef unsigned short ushort_t;
typedef unsigned int uint_t;
typedef short short8 __attribute__((ext_vector_type(8)));
typedef float f32x4 __attribute__((ext_vector_type(4)));

// f32 -> bf16 round-to-nearest-even
static __device__ __forceinline__ ushort_t f2bf(float f) {
    uint_t u = __float_as_uint(f);
    uint_t r = (u + 0x7FFFu + ((u >> 16) & 1u)) >> 16;
    return (ushort_t)r;
}

// ---------------------------------------------------------------------------
// Kernel A: Mt[col][f] = bf16( sum_e (att[r,0]*basis[0,f,e]+att[r,1]*basis[1,f,e]) * fc_w[e,o] )
// ---------------------------------------------------------------------------
__global__ __launch_bounds__(256) void k_make_M(const float* __restrict__ att,
                                                const float* __restrict__ basis,
                                                const float* __restrict__ fcw,
                                                ushort_t* __restrict__ Mt) {
    int tid = blockIdx.x * 256 + threadIdx.x;
    if (tid >= RR * FF * OUTD) return;
    int r = tid / (FF * OUTD);
    int rem = tid - r * FF * OUTD;
    int f = rem >> 6;
    int o = rem & 63;
    float a0 = att[r * 2 + 0], a1 = att[r * 2 + 1];
    const float* b0 = basis + f * EFFD;
    const float* b1 = basis + FF * EFFD + f * EFFD;
    float acc = 0.f;
#pragma unroll 4
    for (int e = 0; e < EFFD; ++e) {
        float w = a0 * b0[e] + a1 * b1[e];
        acc += w * fcw[e * OUTD + o];
    }
    Mt[(size_t)(r * OUTD + o) * FF + f] = f2bf(acc);
}

// ---------------------------------------------------------------------------
// Kernel B (MFMA): g[n][col] = bf16( cj[n] * sum_k feat[n][k] * M[k][col] )
// ---------------------------------------------------------------------------
__global__ __launch_bounds__(256) void k_gemm(const float* __restrict__ featA,
                                              const float* __restrict__ cjA,
                                              const float* __restrict__ featB,
                                              const float* __restrict__ cjB,
                                              const ushort_t* __restrict__ Mt,
                                              ushort_t* __restrict__ gA,
                                              ushort_t* __restrict__ gB) {
    const float* feat; const float* cj; ushort_t* g;
    if (blockIdx.z == 0) { feat = featA; cj = cjA; g = gA; }
    else                 { feat = featB; cj = cjB; g = gB; }

    __shared__ ushort_t featS[64][136];
    __shared__ ushort_t mtS[160][136];

    const int tid  = threadIdx.x;
    const int row0 = blockIdx.x * 64;
    const int ch0  = blockIdx.y * 160;

    for (int i = tid; i < 64 * 32; i += 256) {
        int r  = i >> 5;
        int c4 = (i & 31) << 2;
        float4 v = make_float4(0.f, 0.f, 0.f, 0.f);
        int row = row0 + r;
        if (row < NDRUG) v = *(const float4*)(feat + (size_t)row * FF + c4);
        ushort4 pk;
        pk.x = f2bf(v.x); pk.y = f2bf(v.y); pk.z = f2bf(v.z); pk.w = f2bf(v.w);
        *(ushort4*)&featS[r][c4] = pk;
    }
    for (int i = tid; i < 160 * 16; i += 256) {
        int c  = i >> 4;
        int q8 = (i & 15) << 3;
        *(short8*)&mtS[c][q8] = *(const short8*)(Mt + (size_t)(ch0 + c) * FF + q8);
    }
    __syncthreads();

    const int w = tid >> 6;
    const int l = tid & 63;
    const int lr = l & 15;
    const int lg = l >> 4;

    short8 afrag[4];
#pragma unroll
    for (int ks = 0; ks < 4; ++ks)
        afrag[ks] = *(const short8*)&featS[w * 16 + lr][ks * 32 + lg * 8];

    const int rbase = row0 + w * 16 + (lg << 2);
    float cjv[4];
#pragma unroll
    for (int rg = 0; rg < 4; ++rg)
        cjv[rg] = (rbase + rg < NDRUG) ? cj[rbase + rg] : 0.f;

#pragma unroll
    for (int n = 0; n < 10; ++n) {
        f32x4 c = {0.f, 0.f, 0.f, 0.f};
#pragma unroll
        for (int ks = 0; ks < 4; ++ks) {
            short8 b = *(const short8*)&mtS[n * 16 + lr][ks * 32 + lg * 8];
            c = __builtin_amdgcn_mfma_f32_16x16x32_bf16(afrag[ks], b, c, 0, 0, 0);
        }
        int col = ch0 + n * 16 + lr;
#pragma unroll
        for (int rg = 0; rg < 4; ++rg) {
            int row = rbase + rg;
            if (row < NDRUG)
                g[(size_t)row * NCOL + col] = f2bf(c[rg] * cjv[rg]);
        }
    }
}

// ---------------------------------------------------------------------------
// Pass 1: coarse partition with block-local aggregation (unchanged from r9).
// Entry: ((dst&255)<<16 | src) into slotted bucket (dir, r, dst>>8).
// ---------------------------------------------------------------------------
__global__ __launch_bounds__(256) void k_part(const int* __restrict__ ed,
                                              const int* __restrict__ ei,
                                              int* __restrict__ tails,
                                              uint_t* __restrict__ coarse) {
    int p = blockIdx.x & (NPART - 1);
    int dir = p >> 2;
    int quarter = p & 3;
    int chunk = blockIdx.x >> 3;
    int r = blockIdx.y;
    const int* dstarr = (dir ? ed : ei) + (size_t)r * EE;
    const int* srcarr = (dir ? ei : ed) + (size_t)r * EE;
    int* tl = tails + (dir * RR + r) * NBKT;
    uint_t* cb = coarse + (size_t)(dir * RR + r) * NBKT * CAP;
    int blo = quarter * QBKT;

    __shared__ uint_t stage[STCAP];
    __shared__ int cnt[QBKT];
    __shared__ int cur[QBKT];
    __shared__ int gpos[QBKT];
    __shared__ int nstage;

    int t = threadIdx.x;
    if (t < QBKT) { cnt[t] = 0; cur[t] = 0; }
    if (t == 0) nstage = 0;
    __syncthreads();

    int lane = t & 63;
    int e0 = chunk * CHUNKE;
    for (int i = e0 + t; i < e0 + CHUNKE; i += 256) {
        int d = __builtin_nontemporal_load(dstarr + i);
        int b = (d >> 8) - blo;
        bool m = ((unsigned)b < (unsigned)QBKT);
        unsigned long long mask = __ballot(m);
        if (mask) {
            int src = m ? __builtin_nontemporal_load(srcarr + i) : 0;
            int nw = __popcll(mask);
            int prefix = __popcll(mask & ((1ull << lane) - 1ull));
            int leader = (int)__ffsll((unsigned long long)mask) - 1;
            int wbase = 0;
            if (lane == leader) wbase = atomicAdd(&nstage, nw);
            wbase = __shfl(wbase, leader);
            if (m) {
                int idx = wbase + prefix;
                if (idx < STCAP) {
                    stage[idx] = ((uint_t)b << 26) | ((uint_t)(d & 255) << 16)
                               | (uint_t)(ushort_t)src;
                    atomicAdd(&cnt[b], 1);
                }
            }
        }
    }
    __syncthreads();

    if (t < QBKT) gpos[t] = atomicAdd(&tl[blo + t], cnt[t]);
    __syncthreads();

    int n = nstage; if (n > STCAP) n = STCAP;
    for (int i = t; i < n; i += 256) {
        uint_t e = stage[i];
        int b = e >> 26;
        int q = atomicAdd(&cur[b], 1);
        int idx = gpos[b] + q;
        if (idx < CAP)
            cb[(size_t)(blo + b) * CAP + idx] = e & 0x00FFFFFFu;
    }
}

// ---------------------------------------------------------------------------
// Pass 2 (replaces k_fine + k_agg): one block per coarse bucket.
// LDS acc[256 dst][64 col] f32 (64 KB). Edge-centric: per pass a wave takes
// 4 edges (16 lanes x 8B of the 128B g-row each), ds_add_f32 into the tile.
// 2-deep unroll keeps 2 gathers in flight. Epilogue: acc*ci + fcb -> out.
// grid: (NBKT, RR, 2) x 512 threads.
// ---------------------------------------------------------------------------
__global__ __launch_bounds__(512) void k_agg2(const ushort_t* __restrict__ gd,
                                              const ushort_t* __restrict__ gi,
                                              const int* __restrict__ tails,
                                              const uint_t* __restrict__ coarse,
                                              const float* __restrict__ ci_drug,
                                              const float* __restrict__ ci_dis,
                                              const float* __restrict__ fcb,
                                              float* __restrict__ out_drug,
                                              float* __restrict__ out_dis) {
    int b = blockIdx.x, r = blockIdx.y, dir = blockIdx.z;
    const ushort_t* g = dir ? gi : gd;
    const float* ci   = dir ? ci_drug : ci_dis;
    float* outp       = dir ? out_drug : out_dis;

    int gb = (dir * RR + r) * NBKT + b;
    const uint_t* cb = coarse + (size_t)gb * CAP;
    int count = tails[gb]; if (count > CAP) count = CAP;

    __shared__ float acc[256 * 64];   // 64 KB

    int t = threadIdx.x;
    // zero the tile
    for (int i = t; i < 256 * 16; i += 512)
        ((float4*)acc)[i] = make_float4(0.f, 0.f, 0.f, 0.f);
    __syncthreads();

    const int w    = t >> 6;          // wave 0..7
    const int lane = t & 63;
    const int sub  = lane >> 4;       // edge slot within pass (0..3)
    const int q    = lane & 15;       // 8B chunk of the 128B row (cols 4q..4q+3)
    const int gcolbase = r * OUTD + q * 4;   // element offset within g row

    // 8 waves x 4 edges = 32 edges per block-pass; 2-deep unrolled -> stride 64
    for (int j0 = w * 4 + sub; j0 < count; j0 += 64) {
        int j1 = j0 + 32;
        bool v1 = j1 < count;

        uint_t e0 = cb[j0];
        uint_t e1 = v1 ? cb[j1] : 0u;

        const uint2* p0 = (const uint2*)(g + (size_t)(e0 & 0xffffu) * NCOL + gcolbase);
        uint2 gv0 = *p0;
        uint2 gv1 = make_uint2(0u, 0u);
        if (v1) gv1 = *(const uint2*)(g + (size_t)(e1 & 0xffffu) * NCOL + gcolbase);

        {
            float* a = acc + (e0 >> 16) * 64 + q * 4;
            atomicAdd(a + 0, __uint_as_float(gv0.x << 16));
            atomicAdd(a + 1, __uint_as_float(gv0.x & 0xffff0000u));
            atomicAdd(a + 2, __uint_as_float(gv0.y << 16));
            atomicAdd(a + 3, __uint_as_float(gv0.y & 0xffff0000u));
        }
        if (v1) {
            float* a = acc + (e1 >> 16) * 64 + q * 4;
            atomicAdd(a + 0, __uint_as_float(gv1.x << 16));
            atomicAdd(a + 1, __uint_as_float(gv1.x & 0xffff0000u));
            atomicAdd(a + 2, __uint_as_float(gv1.y << 16));
            atomicAdd(a + 3, __uint_as_float(gv1.y & 0xffff0000u));
        }
    }
    __syncthreads();

    // epilogue: out[dst][r*64 + o] = acc[dstlow][o] * ci[dst] + fcb[o]
    for (int i = t; i < 256 * 16; i += 512) {
        int row = i >> 4;            // local dst
        int q4  = i & 15;            // float4 index within 64 cols
        int dst = b * 256 + row;
        if (dst >= NDIS) continue;
        float4 v = ((float4*)acc)[row * 16 + q4];
        float civ = ci[dst];
        float4 bb = *(const float4*)(fcb + q4 * 4);
        v.x = v.x * civ + bb.x;
        v.y = v.y * civ + bb.y;
        v.z = v.z * civ + bb.z;
        v.w = v.w * civ + bb.w;
        *(float4*)(outp + (size_t)dst * NCOL + r * OUTD + q4 * 4) = v;
    }
}

// ---------------------------------------------------------------------------
extern "C" void kernel_launch(void* const* d_in, const int* in_sizes, int n_in,
                              void* d_out, int out_size, void* d_ws, size_t ws_size,
                              hipStream_t stream) {
    const float* drug_feat = (const float*)d_in[0];
    const float* dis_feat  = (const float*)d_in[1];
    const float* cj_drug   = (const float*)d_in[2];
    const float* ci_drug   = (const float*)d_in[3];
    const float* cj_dis    = (const float*)d_in[4];
    const float* ci_dis    = (const float*)d_in[5];
    const float* att       = (const float*)d_in[6];
    const float* basis     = (const float*)d_in[7];
    const float* fcw       = (const float*)d_in[8];
    const float* fcb       = (const float*)d_in[9];
    const int*   edge_drug = (const int*)d_in[10];
    const int*   edge_dis  = (const int*)d_in[11];

    float* out      = (float*)d_out;
    float* out_drug = out;
    float* out_dis  = out + (size_t)NDRUG * NCOL;

    // Workspace layout (~98.3 MB):
    //   gd (bf16)   32,000,000 @ 0
    //   gi (bf16)   32,000,000 @ 32,000,000
    //   Mt (bf16)      163,840 @ 64,000,000
    //   tails (int)      7,840 @ 66,200,000
    //   coarse (u32) 32,112,640 @ 66,208,000
    char* ws = (char*)d_ws;
    ushort_t* gd      = (ushort_t*)ws;
    ushort_t* gi      = (ushort_t*)(ws + 32000000);
    ushort_t* Mtb     = (ushort_t*)(ws + 64000000);
    int*      tails   = (int*)(ws + 66200000);
    uint_t*   coarse  = (uint_t*)(ws + 66208000);

    // zero bucket tails
    hipMemsetAsync(tails, 0, NGB * sizeof(int), stream);

    // A: fused att*basis*fc_w -> Mt bf16 [320][128]
    k_make_M<<<dim3((RR * FF * OUTD + 255) / 256), 256, 0, stream>>>(att, basis, fcw, Mtb);

    // B: g = bf16((feat @ M) * cj), both sides (MFMA)
    dim3 ggrid((NDRUG + 63) / 64, 2, 2);
    k_gemm<<<ggrid, 256, 0, stream>>>(drug_feat, cj_drug, dis_feat, cj_dis, Mtb, gd, gi);

    // Coarse partition (dense writes, block-aggregated reservations)
    k_part<<<dim3(NCHUNKE * NPART, RR), 256, 0, stream>>>(edge_drug, edge_dis, tails, coarse);

    // Bucket-level LDS accumulation + fused epilogue
    k_agg2<<<dim3(NBKT, RR, 2), 512, 0, stream>>>(gd, gi, tails, coarse,
                                                  ci_drug, ci_dis, fcb,
                                                  out_drug, out_dis);
}

// Round 11
// 343.816 us; speedup vs baseline: 4.4462x; 4.4462x over previous
//
#include <hip/hip_runtime.h>

// Problem constants
#define NDRUG 50000
#define NDIS  50000
#define RR    5
#define FF    128
#define EFFD  128
#define OUTD  64
#define EE    400000
#define NCOL  (RR * OUTD)        // 320 columns in fused g / out layout [n][r*64+o]
#define NB    (RR * NDIS)        // 250000 bins per direction
#define NEDGE (RR * EE)          // 2,000,000 edges per direction

// Two-level bucket sort
#define NBKT    196              // coarse buckets per (dir,r): dst>>8 (50000/256)
#define CAP     4096             // slot capacity per bucket (avg fill 2048, ~45 sigma headroom)
#define NGB     (2 * RR * NBKT)  // 1960 global buckets
#define QBKT    49               // buckets per dst-quarter (196 = 4*49)
#define STCAP   2048             // LDS staging entries per k_part block

// XCD partitioning for k_part: 8 partitions = dir(2) x dst-quarter(4)
#define NPART   8
#define NCHUNKE 64               // edge chunks per r
#define CHUNKE  (EE / NCHUNKE)   // 6250 edges per chunk

typedef unsigned short ushort_t;
typedef unsigned int uint_t;
typedef short short8 __attribute__((ext_vector_type(8)));
typedef float f32x4 __attribute__((ext_vector_type(4)));

// f32 -> bf16 round-to-nearest-even
static __device__ __forceinline__ ushort_t f2bf(float f) {
    uint_t u = __float_as_uint(f);
    uint_t r = (u + 0x7FFFu + ((u >> 16) & 1u)) >> 16;
    return (ushort_t)r;
}

// ---------------------------------------------------------------------------
// Kernel A: Mt[col][f] = bf16( sum_e (att[r,0]*basis[0,f,e]+att[r,1]*basis[1,f,e]) * fc_w[e,o] )
// ---------------------------------------------------------------------------
__global__ __launch_bounds__(256) void k_make_M(const float* __restrict__ att,
                                                const float* __restrict__ basis,
                                                const float* __restrict__ fcw,
                                                ushort_t* __restrict__ Mt) {
    int tid = blockIdx.x * 256 + threadIdx.x;
    if (tid >= RR * FF * OUTD) return;
    int r = tid / (FF * OUTD);
    int rem = tid - r * FF * OUTD;
    int f = rem >> 6;
    int o = rem & 63;
    float a0 = att[r * 2 + 0], a1 = att[r * 2 + 1];
    const float* b0 = basis + f * EFFD;
    const float* b1 = basis + FF * EFFD + f * EFFD;
    float acc = 0.f;
#pragma unroll 4
    for (int e = 0; e < EFFD; ++e) {
        float w = a0 * b0[e] + a1 * b1[e];
        acc += w * fcw[e * OUTD + o];
    }
    Mt[(size_t)(r * OUTD + o) * FF + f] = f2bf(acc);
}

// ---------------------------------------------------------------------------
// Kernel B (MFMA): g[n][col] = bf16( cj[n] * sum_k feat[n][k] * M[k][col] )
// ---------------------------------------------------------------------------
__global__ __launch_bounds__(256) void k_gemm(const float* __restrict__ featA,
                                              const float* __restrict__ cjA,
                                              const float* __restrict__ featB,
                                              const float* __restrict__ cjB,
                                              const ushort_t* __restrict__ Mt,
                                              ushort_t* __restrict__ gA,
                                              ushort_t* __restrict__ gB) {
    const float* feat; const float* cj; ushort_t* g;
    if (blockIdx.z == 0) { feat = featA; cj = cjA; g = gA; }
    else                 { feat = featB; cj = cjB; g = gB; }

    __shared__ ushort_t featS[64][136];
    __shared__ ushort_t mtS[160][136];

    const int tid  = threadIdx.x;
    const int row0 = blockIdx.x * 64;
    const int ch0  = blockIdx.y * 160;

    for (int i = tid; i < 64 * 32; i += 256) {
        int r  = i >> 5;
        int c4 = (i & 31) << 2;
        float4 v = make_float4(0.f, 0.f, 0.f, 0.f);
        int row = row0 + r;
        if (row < NDRUG) v = *(const float4*)(feat + (size_t)row * FF + c4);
        ushort4 pk;
        pk.x = f2bf(v.x); pk.y = f2bf(v.y); pk.z = f2bf(v.z); pk.w = f2bf(v.w);
        *(ushort4*)&featS[r][c4] = pk;
    }
    for (int i = tid; i < 160 * 16; i += 256) {
        int c  = i >> 4;
        int q8 = (i & 15) << 3;
        *(short8*)&mtS[c][q8] = *(const short8*)(Mt + (size_t)(ch0 + c) * FF + q8);
    }
    __syncthreads();

    const int w = tid >> 6;
    const int l = tid & 63;
    const int lr = l & 15;
    const int lg = l >> 4;

    short8 afrag[4];
#pragma unroll
    for (int ks = 0; ks < 4; ++ks)
        afrag[ks] = *(const short8*)&featS[w * 16 + lr][ks * 32 + lg * 8];

    const int rbase = row0 + w * 16 + (lg << 2);
    float cjv[4];
#pragma unroll
    for (int rg = 0; rg < 4; ++rg)
        cjv[rg] = (rbase + rg < NDRUG) ? cj[rbase + rg] : 0.f;

#pragma unroll
    for (int n = 0; n < 10; ++n) {
        f32x4 c = {0.f, 0.f, 0.f, 0.f};
#pragma unroll
        for (int ks = 0; ks < 4; ++ks) {
            short8 b = *(const short8*)&mtS[n * 16 + lr][ks * 32 + lg * 8];
            c = __builtin_amdgcn_mfma_f32_16x16x32_bf16(afrag[ks], b, c, 0, 0, 0);
        }
        int col = ch0 + n * 16 + lr;
#pragma unroll
        for (int rg = 0; rg < 4; ++rg) {
            int row = rbase + rg;
            if (row < NDRUG)
                g[(size_t)row * NCOL + col] = f2bf(c[rg] * cjv[rg]);
        }
    }
}

// ---------------------------------------------------------------------------
// Pass 1: coarse partition with block-local aggregation.
// Entry: ((dst&255)<<16 | src) into slotted bucket (dir, r, dst>>8).
// ---------------------------------------------------------------------------
__global__ __launch_bounds__(256) void k_part(const int* __restrict__ ed,
                                              const int* __restrict__ ei,
                                              int* __restrict__ tails,
                                              uint_t* __restrict__ coarse) {
    int p = blockIdx.x & (NPART - 1);
    int dir = p >> 2;
    int quarter = p & 3;
    int chunk = blockIdx.x >> 3;
    int r = blockIdx.y;
    const int* dstarr = (dir ? ed : ei) + (size_t)r * EE;
    const int* srcarr = (dir ? ei : ed) + (size_t)r * EE;
    int* tl = tails + (dir * RR + r) * NBKT;
    uint_t* cb = coarse + (size_t)(dir * RR + r) * NBKT * CAP;
    int blo = quarter * QBKT;

    __shared__ uint_t stage[STCAP];
    __shared__ int cnt[QBKT];
    __shared__ int cur[QBKT];
    __shared__ int gpos[QBKT];
    __shared__ int nstage;

    int t = threadIdx.x;
    if (t < QBKT) { cnt[t] = 0; cur[t] = 0; }
    if (t == 0) nstage = 0;
    __syncthreads();

    int lane = t & 63;
    int e0 = chunk * CHUNKE;
    for (int i = e0 + t; i < e0 + CHUNKE; i += 256) {
        int d = __builtin_nontemporal_load(dstarr + i);
        int b = (d >> 8) - blo;
        bool m = ((unsigned)b < (unsigned)QBKT);
        unsigned long long mask = __ballot(m);
        if (mask) {
            int src = m ? __builtin_nontemporal_load(srcarr + i) : 0;
            int nw = __popcll(mask);
            int prefix = __popcll(mask & ((1ull << lane) - 1ull));
            int leader = (int)__ffsll((unsigned long long)mask) - 1;
            int wbase = 0;
            if (lane == leader) wbase = atomicAdd(&nstage, nw);
            wbase = __shfl(wbase, leader);
            if (m) {
                int idx = wbase + prefix;
                if (idx < STCAP) {
                    stage[idx] = ((uint_t)b << 26) | ((uint_t)(d & 255) << 16)
                               | (uint_t)(ushort_t)src;
                    atomicAdd(&cnt[b], 1);
                }
            }
        }
    }
    __syncthreads();

    if (t < QBKT) gpos[t] = atomicAdd(&tl[blo + t], cnt[t]);
    __syncthreads();

    int n = nstage; if (n > STCAP) n = STCAP;
    for (int i = t; i < n; i += 256) {
        uint_t e = stage[i];
        int b = e >> 26;
        int q = atomicAdd(&cur[b], 1);
        int idx = gpos[b] + q;
        if (idx < CAP)
            cb[(size_t)(blo + b) * CAP + idx] = e & 0x00FFFFFFu;
    }
}

// ---------------------------------------------------------------------------
// Pass 2: fine counting sort within each bucket (one block per bucket).
// grid: (NBKT, RR, 2)
// ---------------------------------------------------------------------------
__global__ __launch_bounds__(256) void k_fine(const uint_t* __restrict__ coarse,
                                              const int* __restrict__ tails,
                                              ushort_t* __restrict__ sorted,
                                              int* __restrict__ bins) {
    int b = blockIdx.x, r = blockIdx.y, dir = blockIdx.z;
    int gb = (dir * RR + r) * NBKT + b;
    size_t base = (size_t)gb * CAP;
    int count = tails[gb]; if (count > CAP) count = CAP;
    int t = threadIdx.x;

    __shared__ int cnt[256];
    __shared__ int incl[256];
    __shared__ int cur[256];

    cnt[t] = 0;
    __syncthreads();
    for (int i = t; i < count; i += 256)
        atomicAdd(&cnt[coarse[base + i] >> 16], 1);
    __syncthreads();

    int v = cnt[t];
    incl[t] = v;
    __syncthreads();
    for (int off = 1; off < 256; off <<= 1) {
        int x = (t >= off) ? incl[t - off] : 0;
        __syncthreads();
        incl[t] += x;
        __syncthreads();
    }
    int excl = incl[t] - v;
    cur[t] = excl;

    int d = b * 256 + t;
    if (d < NDIS)
        bins[dir * NB + r * NDIS + d] = (int)base + incl[t];   // absolute inclusive end
    __syncthreads();

    for (int i = t; i < count; i += 256) {
        uint_t e = coarse[base + i];
        int p = atomicAdd(&cur[e >> 16], 1);
        sorted[base + p] = (ushort_t)e;
    }
}

// ---------------------------------------------------------------------------
// Gather aggregation + fused epilogue. One wave per (dst, r) bin.
// 2 cols/lane (uint = 2 bf16), 2 edges in flight per wave instruction:
// lanes 0-31 process even edge of the pair, lanes 32-63 the odd edge.
// 4 pairs (8 edges) issued per load block to keep gathers in flight.
// Cross-half __shfl_xor(.,32) reduce, lanes<32 write float2 with ci+bias.
// ---------------------------------------------------------------------------
__global__ __launch_bounds__(256) void k_agg(const ushort_t* __restrict__ gd,
                                             const ushort_t* __restrict__ gi,
                                             const int* __restrict__ bins,
                                             const ushort_t* __restrict__ sorted,
                                             const float* __restrict__ ci_drug,
                                             const float* __restrict__ ci_dis,
                                             const float* __restrict__ fcb,
                                             float* __restrict__ out_drug,
                                             float* __restrict__ out_dis) {
    int dir = blockIdx.y;
    const ushort_t* g   = dir ? gi : gd;
    const float* ci     = dir ? ci_drug : ci_dis;
    float* outp         = dir ? out_drug : out_dis;
    const int* bn       = bins + dir * NB;
    const ushort_t* srt = sorted;

    int wave = blockIdx.x * 4 + (threadIdx.x >> 6);
    int lane = threadIdx.x & 63;
    if (wave >= NB) return;
    int r = wave / NDIS;
    int dst = wave - r * NDIS;
    int gb = (dir * RR + r) * NBKT + (dst >> 8);
    int start = (dst & 255) ? bn[wave - 1] : gb * CAP;
    int end = bn[wave];

    const int half = lane >> 5;            // which edge of the pair
    const int q    = lane & 31;            // uint index: cols 2q, 2q+1
    const ushort_t* grow = g + r * OUTD + q * 2;

    float a0 = 0.f, a1 = 0.f;
    for (int base = start; base < end; base += 64) {
        int m = end - base; if (m > 64) m = 64;
        int li = lane < m ? lane : m - 1;
        int my = (int)srt[(size_t)base + li];
        for (int j = 0; j < m; j += 8) {
            uint_t u[4];
#pragma unroll
            for (int k = 0; k < 4; ++k) {
                int jj = j + 2 * k + half;
                int cl = jj < m ? jj : m - 1;
                int sj = __shfl(my, cl);
                u[k] = *(const uint_t*)(grow + (size_t)sj * NCOL);
            }
#pragma unroll
            for (int k = 0; k < 4; ++k) {
                int jj = j + 2 * k + half;
                uint_t um = jj < m ? u[k] : 0u;
                a0 += __uint_as_float(um << 16);
                a1 += __uint_as_float(um & 0xffff0000u);
            }
        }
    }
    a0 += __shfl_xor(a0, 32);
    a1 += __shfl_xor(a1, 32);
    if (half == 0) {
        float civ = ci[dst];
        float2 bb = *(const float2*)(fcb + q * 2);
        float2 v;
        v.x = a0 * civ + bb.x;
        v.y = a1 * civ + bb.y;
        *(float2*)(outp + (size_t)dst * NCOL + r * OUTD + q * 2) = v;
    }
}

// ---------------------------------------------------------------------------
extern "C" void kernel_launch(void* const* d_in, const int* in_sizes, int n_in,
                              void* d_out, int out_size, void* d_ws, size_t ws_size,
                              hipStream_t stream) {
    const float* drug_feat = (const float*)d_in[0];
    const float* dis_feat  = (const float*)d_in[1];
    const float* cj_drug   = (const float*)d_in[2];
    const float* ci_drug   = (const float*)d_in[3];
    const float* cj_dis    = (const float*)d_in[4];
    const float* ci_dis    = (const float*)d_in[5];
    const float* att       = (const float*)d_in[6];
    const float* basis     = (const float*)d_in[7];
    const float* fcw       = (const float*)d_in[8];
    const float* fcb       = (const float*)d_in[9];
    const int*   edge_drug = (const int*)d_in[10];
    const int*   edge_dis  = (const int*)d_in[11];

    float* out      = (float*)d_out;
    float* out_drug = out;
    float* out_dis  = out + (size_t)NDRUG * NCOL;

    // Workspace layout (~114.4 MB):
    //   gd (bf16)   32,000,000 @ 0
    //   gi (bf16)   32,000,000 @ 32,000,000
    //   Mt (bf16)      163,840 @ 64,000,000
    //   bins (int)   2,000,000 @ 64,200,000
    //   tails (int)      7,840 @ 66,200,000
    //   coarse (u32) 32,112,640 @ 66,208,000
    //   sorted (u16) 16,056,320 @ 98,320,640
    char* ws = (char*)d_ws;
    ushort_t* gd      = (ushort_t*)ws;
    ushort_t* gi      = (ushort_t*)(ws + 32000000);
    ushort_t* Mtb     = (ushort_t*)(ws + 64000000);
    int*      bins    = (int*)(ws + 64200000);
    int*      tails   = (int*)(ws + 66200000);
    uint_t*   coarse  = (uint_t*)(ws + 66208000);
    ushort_t* sorted  = (ushort_t*)(ws + 98320640);

    // zero bucket tails
    hipMemsetAsync(tails, 0, NGB * sizeof(int), stream);

    // A: fused att*basis*fc_w -> Mt bf16 [320][128]
    k_make_M<<<dim3((RR * FF * OUTD + 255) / 256), 256, 0, stream>>>(att, basis, fcw, Mtb);

    // B: g = bf16((feat @ M) * cj), both sides (MFMA)
    dim3 ggrid((NDRUG + 63) / 64, 2, 2);
    k_gemm<<<ggrid, 256, 0, stream>>>(drug_feat, cj_drug, dis_feat, cj_dis, Mtb, gd, gi);

    // Two-level bucket sort (dense writes, block-aggregated reservations)
    k_part<<<dim3(NCHUNKE * NPART, RR), 256, 0, stream>>>(edge_drug, edge_dis, tails, coarse);
    k_fine<<<dim3(NBKT, RR, 2), 256, 0, stream>>>(coarse, tails, sorted, bins);

    // Gather aggregation + fused ci-scale + bias (2 cols/lane, 2 edges/instr)
    k_agg<<<dim3((NB + 3) / 4, 2), 256, 0, stream>>>(gd, gi, bins, sorted,
                                                     ci_drug, ci_dis, fcb,
                                                     out_drug, out_dis);
}